// Round 1
// baseline (56.633 us; speedup 1.0000x reference)
//
#include <hip/hip_runtime.h>

// LIF neuron scan: x [64, 1024, 512] f32 -> spikes [64, 1024, 512] f32 (0/1)
// m = 0.95*m + x[t]; s = (m > 0.5); m = s ? 0 : m
// Sequential over t, parallel over (b, f) = 32768 chains.

#define BATCH 64
#define SEQ   1024
#define FEAT  512
#define UNROLL 16

__global__ __launch_bounds__(64, 1)
void lif_kernel(const float* __restrict__ x, float* __restrict__ out) {
    const int tid = blockIdx.x * blockDim.x + threadIdx.x;   // 0..32767
    const int b = tid >> 9;        // / FEAT
    const int f = tid & (FEAT - 1);
    const size_t base = (size_t)b * SEQ * FEAT + f;
    const float* __restrict__ xp = x + base;
    float* __restrict__ op = out + base;

    float m = 0.0f;
    float cur[UNROLL], nxt[UNROLL];

    // prime first chunk
#pragma unroll
    for (int u = 0; u < UNROLL; ++u) cur[u] = xp[(size_t)u * FEAT];

    for (int t0 = 0; t0 < SEQ; t0 += UNROLL) {
        // prefetch next chunk (independent of the m-chain -> stays in flight
        // while the sequential compute below runs)
        if (t0 + UNROLL < SEQ) {
            const float* __restrict__ xn = xp + (size_t)(t0 + UNROLL) * FEAT;
#pragma unroll
            for (int u = 0; u < UNROLL; ++u) nxt[u] = xn[(size_t)u * FEAT];
        }

        // sequential LIF update; NO fma contraction (np ref rounds mul then add,
        // and the 0/1 threshold makes ulp differences avalanche)
#pragma unroll
        for (int u = 0; u < UNROLL; ++u) {
            m = __fadd_rn(__fmul_rn(0.95f, m), cur[u]);
            const bool fired = (m > 0.5f);
            op[(size_t)(t0 + u) * FEAT] = fired ? 1.0f : 0.0f;
            m = fired ? 0.0f : m;
        }

#pragma unroll
        for (int u = 0; u < UNROLL; ++u) cur[u] = nxt[u];
    }
}

extern "C" void kernel_launch(void* const* d_in, const int* in_sizes, int n_in,
                              void* d_out, int out_size, void* d_ws, size_t ws_size,
                              hipStream_t stream) {
    const float* x = (const float*)d_in[0];
    float* out = (float*)d_out;
    const int total_threads = BATCH * FEAT;      // 32768
    const int block = 64;
    const int grid = total_threads / block;      // 512 blocks -> 2 waves/CU
    lif_kernel<<<grid, block, 0, stream>>>(x, out);
}

// Round 2
// 49.055 us; speedup vs baseline: 1.1545x; 1.1545x over previous
//
#include <hip/hip_runtime.h>

// LIF neuron scan: x [64, 1024, 512] f32 -> spikes [64, 1024, 512] f32 (0/1)
// m = 0.95*m + x[t]; s = (m > 0.5); m = s ? 0 : m
// Sequential over t, parallel over (b, f) = 32768 chains (512 waves, ~2/CU).
// Latency hiding is pure ILP: 32 outstanding dword loads/lane = 4 MB in
// flight grid-wide (> ~2.4 MB latency-BW product at 900cy/6.3TB/s).
// Output is streamed with non-temporal stores so it doesn't evict x from
// the 256 MB L3 across graph replays (x = 128 MB, L3-cacheable).

#define BATCH 64
#define SEQ   1024
#define FEAT  512
#define UNROLL 32

__global__ __launch_bounds__(64, 1)
void lif_kernel(const float* __restrict__ x, float* __restrict__ out) {
    const int tid = blockIdx.x * blockDim.x + threadIdx.x;   // 0..32767
    const int b = tid >> 9;        // / FEAT
    const int f = tid & (FEAT - 1);
    const size_t base = (size_t)b * SEQ * FEAT + f;
    const float* __restrict__ xp = x + base;
    float* __restrict__ op = out + base;

    float m = 0.0f;
    float cur[UNROLL], nxt[UNROLL];

    // prime first chunk
#pragma unroll
    for (int u = 0; u < UNROLL; ++u) cur[u] = xp[(size_t)u * FEAT];

    for (int t0 = 0; t0 < SEQ; t0 += UNROLL) {
        // prefetch next chunk (independent of the m-chain -> stays in flight
        // while the sequential compute below runs)
        if (t0 + UNROLL < SEQ) {
            const float* __restrict__ xn = xp + (size_t)(t0 + UNROLL) * FEAT;
#pragma unroll
            for (int u = 0; u < UNROLL; ++u) nxt[u] = xn[(size_t)u * FEAT];
        }

        // sequential LIF update; NO fma contraction (np ref rounds mul then
        // add separately, and the 0/1 threshold makes ulp differences
        // avalanche down the chain)
#pragma unroll
        for (int u = 0; u < UNROLL; ++u) {
            m = __fadd_rn(__fmul_rn(0.95f, m), cur[u]);
            const bool fired = (m > 0.5f);
            __builtin_nontemporal_store(fired ? 1.0f : 0.0f,
                                        &op[(size_t)(t0 + u) * FEAT]);
            m = fired ? 0.0f : m;
        }

#pragma unroll
        for (int u = 0; u < UNROLL; ++u) cur[u] = nxt[u];
    }
}

extern "C" void kernel_launch(void* const* d_in, const int* in_sizes, int n_in,
                              void* d_out, int out_size, void* d_ws, size_t ws_size,
                              hipStream_t stream) {
    const float* x = (const float*)d_in[0];
    float* out = (float*)d_out;
    const int total_threads = BATCH * FEAT;      // 32768
    const int block = 64;
    const int grid = total_threads / block;      // 512 blocks -> 2 waves/CU
    lif_kernel<<<grid, block, 0, stream>>>(x, out);
}

// Round 3
// 46.935 us; speedup vs baseline: 1.2066x; 1.0452x over previous
//
#include <hip/hip_runtime.h>

// LIF neuron scan: x [64, 1024, 512] f32 -> spikes [64, 1024, 512] f32 (0/1)
// m = 0.95*m + x[t]; s = (m > 0.5); m = s ? 0 : m
// Sequential over t, parallel over (b, f) = 32768 chains (512 waves, 2/CU).
//
// Parallelism is fixed at 32768 lanes, so grid in-flight bytes =
// 32768 lanes x 4B x per-wave load depth. Depth is the only lever
// (vmcnt caps at 63 outstanding VMEM ops/wave). CHUNK=64 with a static
// ping-pong double buffer keeps ~64 loads in flight (~8 MB grid-wide),
// past the queueing knee that limited the CHUNK=32 version to 5.2 TB/s.
// Non-fused mul/add (np ref rounds separately; the 0/1 threshold makes
// ulp differences avalanche). nt stores keep the write-once output from
// evicting x in L3.

#define BATCH 64
#define SEQ   1024
#define FEAT  512
#define CHUNK 64

#define LOAD_CHUNK(buf, t0)                                              \
    {                                                                    \
        const float* __restrict__ xn = xp + (size_t)(t0) * FEAT;         \
        _Pragma("unroll")                                                \
        for (int u = 0; u < CHUNK; ++u) buf[u] = xn[(size_t)u * FEAT];   \
    }

#define COMPUTE_CHUNK(buf, t0)                                           \
    {                                                                    \
        float* __restrict__ on = op + (size_t)(t0) * FEAT;               \
        _Pragma("unroll")                                                \
        for (int u = 0; u < CHUNK; ++u) {                                \
            m = __fadd_rn(__fmul_rn(0.95f, m), buf[u]);                  \
            const bool fired = (m > 0.5f);                               \
            __builtin_nontemporal_store(fired ? 1.0f : 0.0f,             \
                                        &on[(size_t)u * FEAT]);          \
            m = fired ? 0.0f : m;                                        \
        }                                                                \
    }

__global__ __launch_bounds__(64, 1)
void lif_kernel(const float* __restrict__ x, float* __restrict__ out) {
    const int tid = blockIdx.x * blockDim.x + threadIdx.x;   // 0..32767
    const int b = tid >> 9;        // / FEAT
    const int f = tid & (FEAT - 1);
    const size_t base = (size_t)b * SEQ * FEAT + f;
    const float* __restrict__ xp = x + base;
    float* __restrict__ op = out + base;

    float m = 0.0f;
    float bufA[CHUNK], bufB[CHUNK];

    LOAD_CHUNK(bufA, 0)

    // 1024 / (2*64) = 8 iterations; static ping-pong, no register-copy join
    for (int t0 = 0; t0 < SEQ; t0 += 2 * CHUNK) {
        LOAD_CHUNK(bufB, t0 + CHUNK)          // prefetch while computing A
        COMPUTE_CHUNK(bufA, t0)
        if (t0 + 2 * CHUNK < SEQ) {
            LOAD_CHUNK(bufA, t0 + 2 * CHUNK)  // prefetch while computing B
        }
        COMPUTE_CHUNK(bufB, t0 + CHUNK)
    }
}

extern "C" void kernel_launch(void* const* d_in, const int* in_sizes, int n_in,
                              void* d_out, int out_size, void* d_ws, size_t ws_size,
                              hipStream_t stream) {
    const float* x = (const float*)d_in[0];
    float* out = (float*)d_out;
    const int total_threads = BATCH * FEAT;      // 32768
    const int block = 64;
    const int grid = total_threads / block;      // 512 blocks -> 2 waves/CU
    lif_kernel<<<grid, block, 0, stream>>>(x, out);
}